// Round 20
// baseline (782.522 us; speedup 1.0000x reference)
//
#include <hip/hip_runtime.h>
#include <hip/hip_fp16.h>
#include <math.h>

#define D_MODEL 512
#define D_INNER 1024
#define DT_RANK 32
#define D_STATE 16
#define D_CONV 4
#define NB_LAYERS 3
#define BATCH 64
#define SEQ 201
#define CITY 200
#define M_ROWS (BATCH * SEQ)   // 12864 = 64*201
#define M_PAD 12928            // 128*101, for 128-row MFMA tiles
#define EPS 1e-5f
#define NCH 8                  // scan chunks
#define CL 26                  // chunk length (8*26=208 >= 201)

typedef __attribute__((ext_vector_type(8))) short short8;
typedef __attribute__((ext_vector_type(8))) unsigned short ushort8;
typedef __attribute__((ext_vector_type(4))) float f32x4;

__device__ __forceinline__ float sigmoidf_(float x) { return 1.f / (1.f + __expf(-x)); }

__device__ __forceinline__ unsigned short f2b(float f) {  // RNE fp32->bf16
  union { float f; unsigned int u; } v; v.f = f;
  unsigned int r = (v.u + 0x7fff + ((v.u >> 16) & 1)) >> 16;
  return (unsigned short)r;
}
__device__ __forceinline__ float b2f(unsigned short h) {
  union { unsigned int u; float f; } v; v.u = ((unsigned int)h) << 16; return v.f;
}
__device__ __forceinline__ unsigned short f2h(float f) {
  __half h = __float2half(f); return *(unsigned short*)&h;
}
__device__ __forceinline__ float h2f(unsigned short u) {
  __half h = *(__half*)&u; return __half2float(h);
}

__device__ __forceinline__ void gload_lds16(const void* g, void* l) {
  __builtin_amdgcn_global_load_lds(
      (const __attribute__((address_space(1))) void*)g,
      (__attribute__((address_space(3))) void*)l, 16, 0, 0);
}

// ---- decay vector: e[n] = exp(dtv*Areg[n]). Fast path (Areg[n] == -(n+1), the model's
// A_init=arange structure, detected at runtime): one exp + 15 muls instead of 16 exps. ----
__device__ __forceinline__ void exp_vec(float dtv, const float* __restrict__ Areg,
                                        bool fast, float* __restrict__ e) {
  if (fast) {
    float e1 = __expf(-dtv);
    e[0] = e1;
    e[1] = e1 * e1;
    e[2] = e[1] * e1;
    e[3] = e[1] * e[1];
    e[4] = e[3] * e1;
    e[5] = e[3] * e[1];
    e[6] = e[3] * e[2];
    e[7] = e[3] * e[3];
    e[8] = e[7] * e1;
    e[9] = e[7] * e[1];
    e[10] = e[7] * e[2];
    e[11] = e[7] * e[3];
    e[12] = e[7] * e[4];
    e[13] = e[7] * e[5];
    e[14] = e[7] * e[6];
    e[15] = e[7] * e[7];
  } else {
#pragma unroll
    for (int n = 0; n < D_STATE; ++n) e[n] = __expf(dtv * Areg[n]);
  }
}
__device__ __forceinline__ bool a_is_arange(const float* __restrict__ Areg) {
  bool f = true;
#pragma unroll
  for (int n = 0; n < D_STATE; ++n)
    f = f && (fabsf(Areg[n] + (float)(n + 1)) < 1e-4f * (float)(n + 1));
  return f;
}

// ---------------- fp32 -> bf16 bulk convert (zero-pad tail to n_total) ----------------
__global__ __launch_bounds__(256) void k_f2b(const float* __restrict__ in,
                                             unsigned short* __restrict__ out,
                                             int n, int n_total) {
  int i = blockIdx.x * 256 + threadIdx.x;
  if (i < n) out[i] = f2b(in[i]);
  else if (i < n_total) out[i] = 0;
}

// ---------------- fp32 [nl][inrows][cols] -> bf16 [nl][outrows][cols], zero row-pad ---------
__global__ __launch_bounds__(256) void k_padR(const float* __restrict__ W,
                                              unsigned short* __restrict__ out,
                                              int nl, int inrows, int outrows, int cols) {
  int i = blockIdx.x * 256 + threadIdx.x;
  if (i >= nl * outrows * cols) return;
  int c = i % cols;
  int r = (i / cols) % outrows;
  int L = i / (cols * outrows);
  out[i] = (r < inrows) ? f2b(W[((size_t)L * inrows + r) * cols + c]) : 0;
}

// ---------------- conv weight transpose: cw[L][d][k] -> cwT[L][k][d] (fp32) ----------------
__global__ __launch_bounds__(256) void k_convT(const float* __restrict__ cw,
                                               float* __restrict__ cwT) {
  int i = blockIdx.x * 256 + threadIdx.x;
  if (i >= NB_LAYERS * D_CONV * D_INNER) return;
  int d = i & (D_INNER - 1);
  int k = (i >> 10) & 3;
  int L = i >> 12;
  cwT[i] = cw[((size_t)L * D_INNER + d) * D_CONV + k];
}

// ---------------- embed (writes the residual stream directly) ----------------
__global__ __launch_bounds__(256) void k_embed(const float* __restrict__ x,
                                               const float* __restrict__ W,
                                               const float* __restrict__ b,
                                               float* __restrict__ res) {
  int idx = blockIdx.x * 256 + threadIdx.x;
  if (idx >= M_ROWS * D_MODEL) return;
  int d = idx & (D_MODEL - 1);
  int m = idx >> 9;
  float x0 = x[m * 2 + 0], x1 = x[m * 2 + 1];
  res[idx] = fmaf(x0, W[d * 2 + 0], fmaf(x1, W[d * 2 + 1], b[d]));
}

// ---------------- pure norm: hn = norm(res)*w + b -> bf16 (res not modified) ---------------
__global__ __launch_bounds__(256) void k_norm(const float* __restrict__ res,
                                              unsigned short* __restrict__ out_b,
                                              const float* __restrict__ w,
                                              const float* __restrict__ b,
                                              int mode) {
  int row = blockIdx.x * 4 + (threadIdx.x >> 6);
  int lane = threadIdx.x & 63;
  if (row >= M_ROWS) return;
  const float* rp = res + (size_t)row * D_MODEL;
  float v[8];
#pragma unroll
  for (int j = 0; j < 8; ++j) v[j] = rp[j * 64 + lane];
  float mu = 0.f, rstd;
  if (mode == 0) {
    float s = 0.f;
#pragma unroll
    for (int j = 0; j < 8; ++j) s += v[j];
#pragma unroll
    for (int o = 1; o < 64; o <<= 1) s += __shfl_xor(s, o);
    mu = s * (1.f / D_MODEL);
    float vs = 0.f;
#pragma unroll
    for (int j = 0; j < 8; ++j) { float d0 = v[j] - mu; vs += d0 * d0; }
#pragma unroll
    for (int o = 1; o < 64; o <<= 1) vs += __shfl_xor(vs, o);
    rstd = rsqrtf(vs * (1.f / D_MODEL) + EPS);
  } else {
    float s = 0.f;
#pragma unroll
    for (int j = 0; j < 8; ++j) s += v[j] * v[j];
#pragma unroll
    for (int o = 1; o < 64; o <<= 1) s += __shfl_xor(s, o);
    rstd = rsqrtf(s * (1.f / D_MODEL) + EPS);
  }
#pragma unroll
  for (int j = 0; j < 8; ++j) {
    int c = j * 64 + lane;
    out_b[(size_t)row * D_MODEL + c] = f2b((v[j] - mu) * rstd * w[c] + b[c]);
  }
}

// ---- bf16 MFMA GEMM (single-buffer m97 structure + T1 XCD swizzle + T2 LDS swizzle) -------
// C[M,Nout] = A[M,K]bf16 @ B[N,K]bf16^T. BM=BN=128, BK=64, 256 threads (4 waves, 2x2).
// BOUT: 0=fp32, 1=bf16. ADDRES=1: C += result (fp32). ZGATE=1: cols>=1024 get silu (bf16).
template <int BOUT, int ADDRES, int ZGATE>
__global__ __launch_bounds__(256) void k_gemm_mfma(const unsigned short* __restrict__ A,
                                                   const unsigned short* __restrict__ B,
                                                   void* __restrict__ Cv, int ldc,
                                                   int M, int Nout, int K) {
  __shared__ unsigned short lA[128 * 64];
  __shared__ unsigned short lB[128 * 64];
  int tid = threadIdx.x;
  int wave = tid >> 6, lane = tid & 63;
  // T1: bijective XCD-aware block swizzle (m204)
  int nx = gridDim.x;
  int nwg = nx * gridDim.y;
  int bid = blockIdx.y * nx + blockIdx.x;
  int q = nwg >> 3, rr = nwg & 7;
  int xcd = bid & 7, idx = bid >> 3;
  int swz = (xcd < rr ? xcd * (q + 1) : rr * (q + 1) + (xcd - rr) * q) + idx;
  int bm = (swz / nx) * 128, bn = (swz % nx) * 128;
  int wm = (wave >> 1) * 64, wn = (wave & 1) * 64;
  f32x4 acc[4][4] = {};

  for (int k0 = 0; k0 < K; k0 += 64) {
#pragma unroll
    for (int i = 0; i < 4; ++i) {
      int e = (i * 256 + tid) * 8;   // linear LDS dest
      int r = e >> 6, c = e & 63;
      int csrc = c ^ ((r & 7) << 3);  // inverse-swizzled global source (involution)
      gload_lds16(A + (size_t)(bm + r) * K + k0 + csrc, &lA[e]);
      gload_lds16(B + (size_t)(bn + r) * K + k0 + csrc, &lB[e]);
    }
    __syncthreads();
#pragma unroll
    for (int ks = 0; ks < 2; ++ks) {
      int koff = ks * 32 + (lane >> 4) * 8;
      short8 a[4], b[4];
#pragma unroll
      for (int i = 0; i < 4; ++i) {
        int row = wm + i * 16 + (lane & 15);
        a[i] = *(const short8*)&lA[row * 64 + (koff ^ ((row & 7) << 3))];
      }
#pragma unroll
      for (int j = 0; j < 4; ++j) {
        int row = wn + j * 16 + (lane & 15);
        b[j] = *(const short8*)&lB[row * 64 + (koff ^ ((row & 7) << 3))];
      }
#pragma unroll
      for (int i = 0; i < 4; ++i)
#pragma unroll
        for (int j = 0; j < 4; ++j)
          acc[i][j] = __builtin_amdgcn_mfma_f32_16x16x32_bf16(a[i], b[j], acc[i][j], 0, 0, 0);
    }
    __syncthreads();
  }
  // C/D layout: col = lane&15, row = (lane>>4)*4 + reg   [m89-verified]
#pragma unroll
  for (int i = 0; i < 4; ++i) {
    int row0 = bm + wm + i * 16 + (lane >> 4) * 4;
#pragma unroll
    for (int j = 0; j < 4; ++j) {
      int col = bn + wn + j * 16 + (lane & 15);
#pragma unroll
      for (int r = 0; r < 4; ++r) {
        int m = row0 + r;
        if (m < M && col < Nout) {
          float v = acc[i][j][r];
          if (ADDRES) {
            float* cp = (float*)Cv + (size_t)m * ldc + col;
            *cp = *cp + v;
          } else if (BOUT == 1) {
            if (ZGATE && col >= 1024) v = v * sigmoidf_(v);  // pre-gate z half
            ((unsigned short*)Cv)[(size_t)m * ldc + col] = f2b(v);
          } else {
            ((float*)Cv)[(size_t)m * ldc + col] = v;
          }
        }
      }
    }
  }
}

// ---------------- depthwise causal conv (width 4) + bias + SiLU; 8 d per thread ------------
__global__ __launch_bounds__(256) void k_conv_silu(const unsigned short* __restrict__ xz,
                                                   const float* __restrict__ cwT,
                                                   const float* __restrict__ cb,
                                                   unsigned short* __restrict__ ub) {
  int i = blockIdx.x * 256 + threadIdx.x;
  if (i >= M_ROWS * 128) return;
  int dg = (i & 127) << 3;
  int m = i >> 7;
  int l = m % SEQ;
  float y[8];
  float4 cb0 = *(const float4*)&cb[dg];
  float4 cb1 = *(const float4*)&cb[dg + 4];
  y[0] = cb0.x; y[1] = cb0.y; y[2] = cb0.z; y[3] = cb0.w;
  y[4] = cb1.x; y[5] = cb1.y; y[6] = cb1.z; y[7] = cb1.w;
#pragma unroll
  for (int k = 0; k < D_CONV; ++k) {
    int ls = l - (D_CONV - 1) + k;
    if (ls >= 0) {
      ushort8 xv = *(const ushort8*)&xz[(size_t)(m - (D_CONV - 1) + k) * 2048 + dg];
      float4 w0 = *(const float4*)&cwT[k * D_INNER + dg];
      float4 w1 = *(const float4*)&cwT[k * D_INNER + dg + 4];
      y[0] = fmaf(w0.x, b2f(xv[0]), y[0]);
      y[1] = fmaf(w0.y, b2f(xv[1]), y[1]);
      y[2] = fmaf(w0.z, b2f(xv[2]), y[2]);
      y[3] = fmaf(w0.w, b2f(xv[3]), y[3]);
      y[4] = fmaf(w1.x, b2f(xv[4]), y[4]);
      y[5] = fmaf(w1.y, b2f(xv[5]), y[5]);
      y[6] = fmaf(w1.z, b2f(xv[6]), y[6]);
      y[7] = fmaf(w1.w, b2f(xv[7]), y[7]);
    }
  }
  ushort8 o;
#pragma unroll
  for (int j = 0; j < 8; ++j) { float v = y[j]; v = v * sigmoidf_(v); o[j] = f2b(v); }
  *(ushort8*)&ub[(size_t)m * D_INNER + dg] = o;
}

// ---- fused dt: dot(dt_r, Wd)+bias -> softplus; dt_r = fp32 xdb cols 0..31 (wave-uniform) ---
__device__ __forceinline__ float dt_eval(const float* __restrict__ xq,
                                         const float* __restrict__ Wd, float bias) {
  float a0 = 0.f, a1 = 0.f, a2 = 0.f, a3 = 0.f;
#pragma unroll
  for (int r = 0; r < 2; ++r) {
    float4 q0 = *(const float4*)&xq[r * 16 + 0];
    float4 q1 = *(const float4*)&xq[r * 16 + 4];
    float4 q2 = *(const float4*)&xq[r * 16 + 8];
    float4 q3 = *(const float4*)&xq[r * 16 + 12];
    int o = r * 16;
    a0 = fmaf(q0.x, Wd[o + 0], a0); a0 = fmaf(q0.y, Wd[o + 1], a0);
    a0 = fmaf(q0.z, Wd[o + 2], a0); a0 = fmaf(q0.w, Wd[o + 3], a0);
    a1 = fmaf(q1.x, Wd[o + 4], a1); a1 = fmaf(q1.y, Wd[o + 5], a1);
    a1 = fmaf(q1.z, Wd[o + 6], a1); a1 = fmaf(q1.w, Wd[o + 7], a1);
    a2 = fmaf(q2.x, Wd[o + 8], a2); a2 = fmaf(q2.y, Wd[o + 9], a2);
    a2 = fmaf(q2.z, Wd[o + 10], a2); a2 = fmaf(q2.w, Wd[o + 11], a2);
    a3 = fmaf(q3.x, Wd[o + 12], a3); a3 = fmaf(q3.y, Wd[o + 13], a3);
    a3 = fmaf(q3.z, Wd[o + 14], a3); a3 = fmaf(q3.w, Wd[o + 15], a3);
  }
  float dot = ((a0 + a1) + (a2 + a3)) + bias;
  return (dot > 20.f) ? dot : __logf(1.f + __expf(dot));
}

// ---------------- chunked scan: pass 1 (local scans, h0=0; computes+stores dt fp16) --------
__global__ __launch_bounds__(256) void k_scan_p1(const unsigned short* __restrict__ ub,
                                                 const float* __restrict__ xdb,
                                                 const float* __restrict__ dtW,
                                                 const float* __restrict__ dtb,
                                                 const float* __restrict__ A_log,
                                                 unsigned short* __restrict__ dt,
                                                 unsigned short* __restrict__ L,
                                                 float* __restrict__ dtsum) {
  int tid = threadIdx.x;
  int b = blockIdx.x >> 3, c = blockIdx.x & 7;
  int d = blockIdx.y * 256 + tid;
  int t0 = c * CL, t1 = t0 + CL < SEQ ? t0 + CL : SEQ;
  float Wd[DT_RANK];
#pragma unroll
  for (int r = 0; r < DT_RANK; r += 4) {
    float4 w4 = *(const float4*)&dtW[(size_t)d * DT_RANK + r];
    Wd[r] = w4.x; Wd[r + 1] = w4.y; Wd[r + 2] = w4.z; Wd[r + 3] = w4.w;
  }
  float bias = dtb[d];
  float Areg[D_STATE], hst[D_STATE];
#pragma unroll
  for (int n = 0; n < D_STATE; ++n) {
    Areg[n] = -__expf(A_log[d * D_STATE + n]);
    hst[n] = 0.f;
  }
  bool fast = a_is_arange(Areg);
  float ds = 0.f;
  size_t row0 = (size_t)b * SEQ;
  for (int t = t0; t < t1; ++t) {
    size_t m = row0 + t;
    const float* xq = xdb + m * 64;
    unsigned short dh = f2h(dt_eval(xq, Wd, bias));
    dt[m * D_INNER + d] = dh;
    float dtv = h2f(dh);  // use the ROUNDED value everywhere (consistent with p2)
    float uv = b2f(ub[m * D_INNER + d]);
    float Bv[D_STATE];
#pragma unroll
    for (int qd = 0; qd < 4; ++qd) {
      float4 v4 = *(const float4*)&xq[32 + qd * 4];
      Bv[qd * 4 + 0] = v4.x; Bv[qd * 4 + 1] = v4.y;
      Bv[qd * 4 + 2] = v4.z; Bv[qd * 4 + 3] = v4.w;
    }
    float du = dtv * uv;
    ds += dtv;
    float e[D_STATE];
    exp_vec(dtv, Areg, fast, e);
#pragma unroll
    for (int j = 0; j < D_STATE; ++j)
      hst[j] = fmaf(e[j], hst[j], du * Bv[j]);
  }
  size_t base = ((size_t)(b * NCH + c) * D_INNER + d) * D_STATE;
  ushort8 o0, o1;
#pragma unroll
  for (int j = 0; j < 8; ++j) { o0[j] = f2b(hst[j]); o1[j] = f2b(hst[8 + j]); }
  *(ushort8*)&L[base] = o0;
  *(ushort8*)&L[base + 8] = o1;
  dtsum[(size_t)(b * NCH + c) * D_INNER + d] = ds;
}

// ---------------- chunked scan: fixup (sequential chunk prefix; L -> entry states) --------
__global__ __launch_bounds__(256) void k_scan_fix(const float* __restrict__ A_log,
                                                  const float* __restrict__ dtsum,
                                                  unsigned short* __restrict__ L) {
  int tid = threadIdx.x;
  int b = blockIdx.x;
  int d = blockIdx.y * 256 + tid;
  float Areg[D_STATE], h[D_STATE];
#pragma unroll
  for (int n = 0; n < D_STATE; ++n) {
    Areg[n] = -__expf(A_log[d * D_STATE + n]);
    h[n] = 0.f;
  }
  bool fast = a_is_arange(Areg);
  for (int c = 0; c < NCH; ++c) {
    size_t base = ((size_t)(b * NCH + c) * D_INNER + d) * D_STATE;
    ushort8 l0 = *(const ushort8*)&L[base];
    ushort8 l1 = *(const ushort8*)&L[base + 8];
    float ds = dtsum[(size_t)(b * NCH + c) * D_INNER + d];
    ushort8 o0, o1;
#pragma unroll
    for (int j = 0; j < 8; ++j) { o0[j] = f2b(h[j]); o1[j] = f2b(h[8 + j]); }
    *(ushort8*)&L[base] = o0;
    *(ushort8*)&L[base + 8] = o1;
    float e[D_STATE];
    exp_vec(ds, Areg, fast, e);
#pragma unroll
    for (int j = 0; j < 8; ++j)
      h[j] = fmaf(e[j], h[j], b2f(l0[j]));
#pragma unroll
    for (int j = 0; j < 8; ++j)
      h[8 + j] = fmaf(e[8 + j], h[8 + j], b2f(l1[j]));
  }
}

// ---------------- chunked scan: pass 2 (entry state from fixed-up L; pre-gated z) ----------
__global__ __launch_bounds__(256) void k_scan_p2(const unsigned short* __restrict__ xz,
                                                 const unsigned short* __restrict__ ub,
                                                 const float* __restrict__ xdb,
                                                 const unsigned short* __restrict__ dt,
                                                 const float* __restrict__ A_log,
                                                 const float* __restrict__ Dv,
                                                 const unsigned short* __restrict__ L,
                                                 unsigned short* __restrict__ yb) {
  int tid = threadIdx.x;
  int b = blockIdx.x >> 3, c = blockIdx.x & 7;
  int d = blockIdx.y * 256 + tid;
  int t0 = c * CL, t1 = t0 + CL < SEQ ? t0 + CL : SEQ;
  float Areg[D_STATE], hst[D_STATE];
  size_t base = ((size_t)(b * NCH + c) * D_INNER + d) * D_STATE;
  ushort8 l0 = *(const ushort8*)&L[base];
  ushort8 l1 = *(const ushort8*)&L[base + 8];
#pragma unroll
  for (int n = 0; n < D_STATE; ++n) Areg[n] = -__expf(A_log[d * D_STATE + n]);
  bool fast = a_is_arange(Areg);
#pragma unroll
  for (int j = 0; j < 8; ++j) { hst[j] = b2f(l0[j]); hst[8 + j] = b2f(l1[j]); }
  float Dd = Dv[d];
  size_t row0 = (size_t)b * SEQ;
  for (int t = t0; t < t1; ++t) {
    size_t m = row0 + t;
    const float* xq = xdb + m * 64;
    float dtv = h2f(dt[m * D_INNER + d]);
    float uv = b2f(ub[m * D_INNER + d]);
    float zg = b2f(xz[m * 2048 + 1024 + d]);  // pre-gated silu(z) from in_proj epilogue
    float Bv[D_STATE], Cvv[D_STATE];
#pragma unroll
    for (int qd = 0; qd < 4; ++qd) {
      float4 v4 = *(const float4*)&xq[32 + qd * 4];
      Bv[qd * 4 + 0] = v4.x; Bv[qd * 4 + 1] = v4.y;
      Bv[qd * 4 + 2] = v4.z; Bv[qd * 4 + 3] = v4.w;
      float4 c4 = *(const float4*)&xq[48 + qd * 4];
      Cvv[qd * 4 + 0] = c4.x; Cvv[qd * 4 + 1] = c4.y;
      Cvv[qd * 4 + 2] = c4.z; Cvv[qd * 4 + 3] = c4.w;
    }
    float du = dtv * uv;
    float e[D_STATE];
    exp_vec(dtv, Areg, fast, e);
    float y0 = 0.f, y1 = 0.f, y2 = 0.f, y3 = 0.f;
#pragma unroll
    for (int j = 0; j < D_STATE; ++j) {
      hst[j] = fmaf(e[j], hst[j], du * Bv[j]);
      float& yq = (j < 4) ? y0 : (j < 8) ? y1 : (j < 12) ? y2 : y3;
      yq = fmaf(hst[j], Cvv[j], yq);
    }
    float y = (y0 + y1) + (y2 + y3);
    y = fmaf(Dd, uv, y);
    y = y * zg;
    yb[m * D_INNER + d] = f2b(y);
  }
}

extern "C" void kernel_launch(void* const* d_in, const int* in_sizes, int n_in,
                              void* d_out, int out_size, void* d_ws, size_t ws_size,
                              hipStream_t stream) {
  const float* x        = (const float*)d_in[0];
  const float* embed_W  = (const float*)d_in[2];
  const float* embed_b  = (const float*)d_in[3];
  const float* norm_w   = (const float*)d_in[4];
  const float* norm_b   = (const float*)d_in[5];
  const float* in_W     = (const float*)d_in[6];
  const float* conv_w   = (const float*)d_in[7];
  const float* conv_b   = (const float*)d_in[8];
  const float* xproj_W  = (const float*)d_in[9];
  const float* dtproj_W = (const float*)d_in[10];
  const float* dtproj_b = (const float*)d_in[11];
  const float* A_log    = (const float*)d_in[12];
  const float* Dskip    = (const float*)d_in[13];
  const float* out_W    = (const float*)d_in[14];
  const float* normf_w  = (const float*)d_in[15];
  const float* normf_b  = (const float*)d_in[16];
  const float* head_W   = (const float*)d_in[17];
  float* out = (float*)d_out;

  size_t f32_elems = (size_t)M_ROWS * 512 /* res */ + (size_t)M_PAD * 64 /* xdb */ +
                     (size_t)NB_LAYERS * D_CONV * D_INNER /* cwT */ +
                     (size_t)BATCH * NCH * D_INNER /* dtsum */;
  size_t bf16_elems = (size_t)M_ROWS * 2048 /* xz */ + (size_t)M_PAD * 2048 /* ub+yb */ +
                      (size_t)M_ROWS * 1024 /* dt fp16 */ +
                      (size_t)BATCH * NCH * D_INNER * D_STATE /* L */ +
                      (size_t)NB_LAYERS * (2048 * 512 + 512 * 1024 + 128 * 1024) +
                      256 * 512;
  size_t need = f32_elems * 4 + bf16_elems * 2;
  if (ws_size < need) return;

  float* ws = (float*)d_ws;
  float* buf_res  = ws;                                   // M*512 (residual stream)
  float* buf_xdb  = buf_res  + (size_t)M_ROWS * 512;      // M_PAD*64 fp32
  float* buf_cwT  = buf_xdb  + (size_t)M_PAD * 64;        // 3*4*1024 fp32
  float* buf_dts  = buf_cwT  + (size_t)NB_LAYERS * D_CONV * D_INNER;  // B*NCH*1024 fp32
  unsigned short* buf_xz   = (unsigned short*)(buf_dts + (size_t)BATCH * NCH * D_INNER);
  unsigned short* buf_ub   = buf_xz + (size_t)M_ROWS * 2048;  // M_PAD*1024
  unsigned short* buf_yb   = buf_ub + (size_t)M_PAD * 1024;   // M_PAD*1024 (alias hnb)
  unsigned short* buf_hnb  = buf_yb;                          // M_PAD*512
  unsigned short* buf_dt   = buf_yb + (size_t)M_PAD * 1024;   // M*1024 fp16
  unsigned short* buf_L    = buf_dt + (size_t)M_ROWS * 1024;  // B*NCH*1024*16 bf16
  unsigned short* buf_wib  = buf_L + (size_t)BATCH * NCH * D_INNER * D_STATE;
  unsigned short* buf_wob  = buf_wib + (size_t)NB_LAYERS * 2048 * 512;
  unsigned short* buf_wxb  = buf_wob + (size_t)NB_LAYERS * 512 * 1024;
  unsigned short* buf_whb  = buf_wxb + (size_t)NB_LAYERS * 128 * 1024;

  dim3 blk(256);

  // ---- all-layer weight prep (5 dispatches, once per launch) ----
  k_f2b<<<(NB_LAYERS * 2048 * 512 + 255) / 256, blk, 0, stream>>>(
      in_W, buf_wib, NB_LAYERS * 2048 * 512, NB_LAYERS * 2048 * 512);
  k_f2b<<<(NB_LAYERS * 512 * 1024 + 255) / 256, blk, 0, stream>>>(
      out_W, buf_wob, NB_LAYERS * 512 * 1024, NB_LAYERS * 512 * 1024);
  k_padR<<<(NB_LAYERS * 128 * 1024 + 255) / 256, blk, 0, stream>>>(
      xproj_W, buf_wxb, NB_LAYERS, 64, 128, 1024);
  k_f2b<<<(256 * 512 + 255) / 256, blk, 0, stream>>>(head_W, buf_whb, CITY * 512, 256 * 512);
  k_convT<<<(NB_LAYERS * D_CONV * D_INNER + 255) / 256, blk, 0, stream>>>(conv_w, buf_cwT);

  // embed -> residual stream
  k_embed<<<(M_ROWS * D_MODEL + 255) / 256, blk, 0, stream>>>(x, embed_W, embed_b, buf_res);

  for (int i = 0; i < NB_LAYERS; ++i) {
    // layernorm(res) -> hn (bf16); res untouched
    k_norm<<<(M_ROWS + 3) / 4, blk, 0, stream>>>(
        buf_res, buf_hnb, norm_w + i * D_MODEL, norm_b + i * D_MODEL, 0);

    // in_proj (MFMA, bf16 out, z-half pre-gated): xz = hn @ in_W^T   (M, 2048)
    k_gemm_mfma<1, 0, 1><<<dim3(2048 / 128, M_PAD / 128), blk, 0, stream>>>(
        buf_hnb, buf_wib + (size_t)i * 2048 * 512, buf_xz, 2048, M_ROWS, 2048, 512);

    // conv + silu -> u (bf16); coalesced transposed weights (reads raw xc half only)
    k_conv_silu<<<(M_ROWS * 128 + 255) / 256, blk, 0, stream>>>(
        buf_xz, buf_cwT + (size_t)i * D_CONV * D_INNER, conv_b + (size_t)i * D_INNER, buf_ub);

    // x_proj (MFMA, fp32 out): xdb = u @ xproj_W^T   (M, 64), N padded to 128
    k_gemm_mfma<0, 0, 0><<<dim3(1, M_PAD / 128), blk, 0, stream>>>(
        buf_ub, buf_wxb + (size_t)i * 128 * 1024, buf_xdb, 64, M_ROWS, 64, 1024);

    // chunked scan: p1 -> fixup -> p2
    const float* Ai  = A_log + (size_t)i * D_INNER * D_STATE;
    const float* Wdt = dtproj_W + (size_t)i * D_INNER * DT_RANK;
    const float* bdt = dtproj_b + (size_t)i * D_INNER;
    k_scan_p1<<<dim3(BATCH * NCH, D_INNER / 256), blk, 0, stream>>>(
        buf_ub, buf_xdb, Wdt, bdt, Ai, buf_dt, buf_L, buf_dts);
    k_scan_fix<<<dim3(BATCH, D_INNER / 256), blk, 0, stream>>>(Ai, buf_dts, buf_L);
    k_scan_p2<<<dim3(BATCH * NCH, D_INNER / 256), blk, 0, stream>>>(
        buf_xz, buf_ub, buf_xdb, buf_dt, Ai, Dskip + (size_t)i * D_INNER, buf_L, buf_yb);

    // out_proj (MFMA, residual-fused): res += y @ out_W^T   (M, 512)
    k_gemm_mfma<0, 1, 0><<<dim3(512 / 128, M_PAD / 128), blk, 0, stream>>>(
        buf_yb, buf_wob + (size_t)i * 512 * 1024, buf_res, 512, M_ROWS, 512, 1024);
  }

  // final rmsnorm(res) -> xf (bf16, over hnb region; y dead)
  k_norm<<<(M_ROWS + 3) / 4, blk, 0, stream>>>(buf_res, buf_hnb, normf_w, normf_b, 1);

  // head (MFMA, fp32 out): logits = xf @ head_W^T   (M, 200), N padded to 256
  k_gemm_mfma<0, 0, 0><<<dim3(256 / 128, M_PAD / 128), blk, 0, stream>>>(
      buf_hnb, buf_whb, out, CITY, M_ROWS, CITY, 512);
}

// Round 21
// 741.726 us; speedup vs baseline: 1.0550x; 1.0550x over previous
//
#include <hip/hip_runtime.h>
#include <hip/hip_fp16.h>
#include <math.h>

#define D_MODEL 512
#define D_INNER 1024
#define DT_RANK 32
#define D_STATE 16
#define D_CONV 4
#define NB_LAYERS 3
#define BATCH 64
#define SEQ 201
#define CITY 200
#define M_ROWS (BATCH * SEQ)   // 12864 = 64*201
#define M_PAD 12928            // 128*101, for 128-row MFMA tiles
#define EPS 1e-5f
#define NCH 8                  // scan chunks
#define CL 26                  // chunk length (8*26=208 >= 201)

typedef __attribute__((ext_vector_type(8))) short short8;
typedef __attribute__((ext_vector_type(8))) unsigned short ushort8;
typedef __attribute__((ext_vector_type(4))) float f32x4;

__device__ __forceinline__ float sigmoidf_(float x) { return 1.f / (1.f + __expf(-x)); }

__device__ __forceinline__ unsigned short f2b(float f) {  // RNE fp32->bf16
  union { float f; unsigned int u; } v; v.f = f;
  unsigned int r = (v.u + 0x7fff + ((v.u >> 16) & 1)) >> 16;
  return (unsigned short)r;
}
__device__ __forceinline__ float b2f(unsigned short h) {
  union { unsigned int u; float f; } v; v.u = ((unsigned int)h) << 16; return v.f;
}
__device__ __forceinline__ unsigned short f2h(float f) {
  __half h = __float2half(f); return *(unsigned short*)&h;
}
__device__ __forceinline__ float h2f(unsigned short u) {
  __half h = *(__half*)&u; return __half2float(h);
}

__device__ __forceinline__ void gload_lds16(const void* g, void* l) {
  __builtin_amdgcn_global_load_lds(
      (const __attribute__((address_space(1))) void*)g,
      (__attribute__((address_space(3))) void*)l, 16, 0, 0);
}

// ---- decay vector: e[n] = exp(dtv*Areg[n]). Fast path (Areg[n] == -(n+1), the model's
// A_init=arange structure, detected at runtime): one exp + 15 muls instead of 16 exps. ----
__device__ __forceinline__ void exp_vec(float dtv, const float* __restrict__ Areg,
                                        bool fast, float* __restrict__ e) {
  if (fast) {
    float e1 = __expf(-dtv);
    e[0] = e1;
    e[1] = e1 * e1;
    e[2] = e[1] * e1;
    e[3] = e[1] * e[1];
    e[4] = e[3] * e1;
    e[5] = e[3] * e[1];
    e[6] = e[3] * e[2];
    e[7] = e[3] * e[3];
    e[8] = e[7] * e1;
    e[9] = e[7] * e[1];
    e[10] = e[7] * e[2];
    e[11] = e[7] * e[3];
    e[12] = e[7] * e[4];
    e[13] = e[7] * e[5];
    e[14] = e[7] * e[6];
    e[15] = e[7] * e[7];
  } else {
#pragma unroll
    for (int n = 0; n < D_STATE; ++n) e[n] = __expf(dtv * Areg[n]);
  }
}
__device__ __forceinline__ bool a_is_arange(const float* __restrict__ Areg) {
  bool f = true;
#pragma unroll
  for (int n = 0; n < D_STATE; ++n)
    f = f && (fabsf(Areg[n] + (float)(n + 1)) < 1e-4f * (float)(n + 1));
  return f;
}

// ---------------- fp32 -> bf16 bulk convert (zero-pad tail to n_total) ----------------
__global__ __launch_bounds__(256) void k_f2b(const float* __restrict__ in,
                                             unsigned short* __restrict__ out,
                                             int n, int n_total) {
  int i = blockIdx.x * 256 + threadIdx.x;
  if (i < n) out[i] = f2b(in[i]);
  else if (i < n_total) out[i] = 0;
}

// ---------------- fp32 [nl][inrows][cols] -> bf16 [nl][outrows][cols], zero row-pad ---------
__global__ __launch_bounds__(256) void k_padR(const float* __restrict__ W,
                                              unsigned short* __restrict__ out,
                                              int nl, int inrows, int outrows, int cols) {
  int i = blockIdx.x * 256 + threadIdx.x;
  if (i >= nl * outrows * cols) return;
  int c = i % cols;
  int r = (i / cols) % outrows;
  int L = i / (cols * outrows);
  out[i] = (r < inrows) ? f2b(W[((size_t)L * inrows + r) * cols + c]) : 0;
}

// ---------------- conv weight transpose: cw[L][d][k] -> cwT[L][k][d] (fp32) ----------------
__global__ __launch_bounds__(256) void k_convT(const float* __restrict__ cw,
                                               float* __restrict__ cwT) {
  int i = blockIdx.x * 256 + threadIdx.x;
  if (i >= NB_LAYERS * D_CONV * D_INNER) return;
  int d = i & (D_INNER - 1);
  int k = (i >> 10) & 3;
  int L = i >> 12;
  cwT[i] = cw[((size_t)L * D_INNER + d) * D_CONV + k];
}

// ---------------- embed (writes the residual stream directly) ----------------
__global__ __launch_bounds__(256) void k_embed(const float* __restrict__ x,
                                               const float* __restrict__ W,
                                               const float* __restrict__ b,
                                               float* __restrict__ res) {
  int idx = blockIdx.x * 256 + threadIdx.x;
  if (idx >= M_ROWS * D_MODEL) return;
  int d = idx & (D_MODEL - 1);
  int m = idx >> 9;
  float x0 = x[m * 2 + 0], x1 = x[m * 2 + 1];
  res[idx] = fmaf(x0, W[d * 2 + 0], fmaf(x1, W[d * 2 + 1], b[d]));
}

// ---------------- pure norm: hn = norm(res)*w + b -> bf16 (res not modified) ---------------
__global__ __launch_bounds__(256) void k_norm(const float* __restrict__ res,
                                              unsigned short* __restrict__ out_b,
                                              const float* __restrict__ w,
                                              const float* __restrict__ b,
                                              int mode) {
  int row = blockIdx.x * 4 + (threadIdx.x >> 6);
  int lane = threadIdx.x & 63;
  if (row >= M_ROWS) return;
  const float* rp = res + (size_t)row * D_MODEL;
  float v[8];
#pragma unroll
  for (int j = 0; j < 8; ++j) v[j] = rp[j * 64 + lane];
  float mu = 0.f, rstd;
  if (mode == 0) {
    float s = 0.f;
#pragma unroll
    for (int j = 0; j < 8; ++j) s += v[j];
#pragma unroll
    for (int o = 1; o < 64; o <<= 1) s += __shfl_xor(s, o);
    mu = s * (1.f / D_MODEL);
    float vs = 0.f;
#pragma unroll
    for (int j = 0; j < 8; ++j) { float d0 = v[j] - mu; vs += d0 * d0; }
#pragma unroll
    for (int o = 1; o < 64; o <<= 1) vs += __shfl_xor(vs, o);
    rstd = rsqrtf(vs * (1.f / D_MODEL) + EPS);
  } else {
    float s = 0.f;
#pragma unroll
    for (int j = 0; j < 8; ++j) s += v[j] * v[j];
#pragma unroll
    for (int o = 1; o < 64; o <<= 1) s += __shfl_xor(s, o);
    rstd = rsqrtf(s * (1.f / D_MODEL) + EPS);
  }
#pragma unroll
  for (int j = 0; j < 8; ++j) {
    int c = j * 64 + lane;
    out_b[(size_t)row * D_MODEL + c] = f2b((v[j] - mu) * rstd * w[c] + b[c]);
  }
}

// ---- bf16 MFMA GEMM (single-buffer m97 structure + T1 XCD swizzle + T2 LDS swizzle) -------
// C[M,Nout] = A[M,K]bf16 @ B[N,K]bf16^T. BM=BN=128, BK=64, 256 threads (4 waves, 2x2).
// BOUT: 0=fp32, 1=bf16. ADDRES=1: C += result (residual fuse, fp32 only).
template <int BOUT, int ADDRES>
__global__ __launch_bounds__(256) void k_gemm_mfma(const unsigned short* __restrict__ A,
                                                   const unsigned short* __restrict__ B,
                                                   void* __restrict__ Cv, int ldc,
                                                   int M, int Nout, int K) {
  __shared__ unsigned short lA[128 * 64];
  __shared__ unsigned short lB[128 * 64];
  int tid = threadIdx.x;
  int wave = tid >> 6, lane = tid & 63;
  // T1: bijective XCD-aware block swizzle (m204)
  int nx = gridDim.x;
  int nwg = nx * gridDim.y;
  int bid = blockIdx.y * nx + blockIdx.x;
  int q = nwg >> 3, rr = nwg & 7;
  int xcd = bid & 7, idx = bid >> 3;
  int swz = (xcd < rr ? xcd * (q + 1) : rr * (q + 1) + (xcd - rr) * q) + idx;
  int bm = (swz / nx) * 128, bn = (swz % nx) * 128;
  int wm = (wave >> 1) * 64, wn = (wave & 1) * 64;
  f32x4 acc[4][4] = {};

  for (int k0 = 0; k0 < K; k0 += 64) {
#pragma unroll
    for (int i = 0; i < 4; ++i) {
      int e = (i * 256 + tid) * 8;   // linear LDS dest
      int r = e >> 6, c = e & 63;
      int csrc = c ^ ((r & 7) << 3);  // inverse-swizzled global source (involution)
      gload_lds16(A + (size_t)(bm + r) * K + k0 + csrc, &lA[e]);
      gload_lds16(B + (size_t)(bn + r) * K + k0 + csrc, &lB[e]);
    }
    __syncthreads();
#pragma unroll
    for (int ks = 0; ks < 2; ++ks) {
      int koff = ks * 32 + (lane >> 4) * 8;
      short8 a[4], b[4];
#pragma unroll
      for (int i = 0; i < 4; ++i) {
        int row = wm + i * 16 + (lane & 15);
        a[i] = *(const short8*)&lA[row * 64 + (koff ^ ((row & 7) << 3))];
      }
#pragma unroll
      for (int j = 0; j < 4; ++j) {
        int row = wn + j * 16 + (lane & 15);
        b[j] = *(const short8*)&lB[row * 64 + (koff ^ ((row & 7) << 3))];
      }
#pragma unroll
      for (int i = 0; i < 4; ++i)
#pragma unroll
        for (int j = 0; j < 4; ++j)
          acc[i][j] = __builtin_amdgcn_mfma_f32_16x16x32_bf16(a[i], b[j], acc[i][j], 0, 0, 0);
    }
    __syncthreads();
  }
  // C/D layout: col = lane&15, row = (lane>>4)*4 + reg   [m89-verified]
#pragma unroll
  for (int i = 0; i < 4; ++i) {
    int row0 = bm + wm + i * 16 + (lane >> 4) * 4;
#pragma unroll
    for (int j = 0; j < 4; ++j) {
      int col = bn + wn + j * 16 + (lane & 15);
#pragma unroll
      for (int r = 0; r < 4; ++r) {
        int m = row0 + r;
        if (m < M && col < Nout) {
          float v = acc[i][j][r];
          if (ADDRES) {
            float* cp = (float*)Cv + (size_t)m * ldc + col;
            *cp = *cp + v;
          } else if (BOUT == 1) {
            ((unsigned short*)Cv)[(size_t)m * ldc + col] = f2b(v);
          } else {
            ((float*)Cv)[(size_t)m * ldc + col] = v;
          }
        }
      }
    }
  }
}

// ---------------- depthwise causal conv (width 4) + bias + SiLU; 8 d per thread ------------
__global__ __launch_bounds__(256) void k_conv_silu(const unsigned short* __restrict__ xz,
                                                   const float* __restrict__ cwT,
                                                   const float* __restrict__ cb,
                                                   unsigned short* __restrict__ ub) {
  int i = blockIdx.x * 256 + threadIdx.x;
  if (i >= M_ROWS * 128) return;
  int dg = (i & 127) << 3;
  int m = i >> 7;
  int l = m % SEQ;
  float y[8];
  float4 cb0 = *(const float4*)&cb[dg];
  float4 cb1 = *(const float4*)&cb[dg + 4];
  y[0] = cb0.x; y[1] = cb0.y; y[2] = cb0.z; y[3] = cb0.w;
  y[4] = cb1.x; y[5] = cb1.y; y[6] = cb1.z; y[7] = cb1.w;
#pragma unroll
  for (int k = 0; k < D_CONV; ++k) {
    int ls = l - (D_CONV - 1) + k;
    if (ls >= 0) {
      ushort8 xv = *(const ushort8*)&xz[(size_t)(m - (D_CONV - 1) + k) * 2048 + dg];
      float4 w0 = *(const float4*)&cwT[k * D_INNER + dg];
      float4 w1 = *(const float4*)&cwT[k * D_INNER + dg + 4];
      y[0] = fmaf(w0.x, b2f(xv[0]), y[0]);
      y[1] = fmaf(w0.y, b2f(xv[1]), y[1]);
      y[2] = fmaf(w0.z, b2f(xv[2]), y[2]);
      y[3] = fmaf(w0.w, b2f(xv[3]), y[3]);
      y[4] = fmaf(w1.x, b2f(xv[4]), y[4]);
      y[5] = fmaf(w1.y, b2f(xv[5]), y[5]);
      y[6] = fmaf(w1.z, b2f(xv[6]), y[6]);
      y[7] = fmaf(w1.w, b2f(xv[7]), y[7]);
    }
  }
  ushort8 o;
#pragma unroll
  for (int j = 0; j < 8; ++j) { float v = y[j]; v = v * sigmoidf_(v); o[j] = f2b(v); }
  *(ushort8*)&ub[(size_t)m * D_INNER + dg] = o;
}

// ---- fused dt: dot(dt_r, Wd)+bias -> softplus; dt_r = fp32 xdb cols 0..31 (wave-uniform) ---
__device__ __forceinline__ float dt_eval(const float* __restrict__ xq,
                                         const float* __restrict__ Wd, float bias) {
  float a0 = 0.f, a1 = 0.f, a2 = 0.f, a3 = 0.f;
#pragma unroll
  for (int r = 0; r < 2; ++r) {
    float4 q0 = *(const float4*)&xq[r * 16 + 0];
    float4 q1 = *(const float4*)&xq[r * 16 + 4];
    float4 q2 = *(const float4*)&xq[r * 16 + 8];
    float4 q3 = *(const float4*)&xq[r * 16 + 12];
    int o = r * 16;
    a0 = fmaf(q0.x, Wd[o + 0], a0); a0 = fmaf(q0.y, Wd[o + 1], a0);
    a0 = fmaf(q0.z, Wd[o + 2], a0); a0 = fmaf(q0.w, Wd[o + 3], a0);
    a1 = fmaf(q1.x, Wd[o + 4], a1); a1 = fmaf(q1.y, Wd[o + 5], a1);
    a1 = fmaf(q1.z, Wd[o + 6], a1); a1 = fmaf(q1.w, Wd[o + 7], a1);
    a2 = fmaf(q2.x, Wd[o + 8], a2); a2 = fmaf(q2.y, Wd[o + 9], a2);
    a2 = fmaf(q2.z, Wd[o + 10], a2); a2 = fmaf(q2.w, Wd[o + 11], a2);
    a3 = fmaf(q3.x, Wd[o + 12], a3); a3 = fmaf(q3.y, Wd[o + 13], a3);
    a3 = fmaf(q3.z, Wd[o + 14], a3); a3 = fmaf(q3.w, Wd[o + 15], a3);
  }
  float dot = ((a0 + a1) + (a2 + a3)) + bias;
  return (dot > 20.f) ? dot : __logf(1.f + __expf(dot));
}

// ---------------- chunked scan: pass 1 (local scans, h0=0; computes+stores dt fp16) --------
__global__ __launch_bounds__(256) void k_scan_p1(const unsigned short* __restrict__ ub,
                                                 const float* __restrict__ xdb,
                                                 const float* __restrict__ dtW,
                                                 const float* __restrict__ dtb,
                                                 const float* __restrict__ A_log,
                                                 unsigned short* __restrict__ dt,
                                                 unsigned short* __restrict__ L,
                                                 float* __restrict__ dtsum) {
  int tid = threadIdx.x;
  int b = blockIdx.x >> 3, c = blockIdx.x & 7;
  int d = blockIdx.y * 256 + tid;
  int t0 = c * CL, t1 = t0 + CL < SEQ ? t0 + CL : SEQ;
  float Wd[DT_RANK];
#pragma unroll
  for (int r = 0; r < DT_RANK; r += 4) {
    float4 w4 = *(const float4*)&dtW[(size_t)d * DT_RANK + r];
    Wd[r] = w4.x; Wd[r + 1] = w4.y; Wd[r + 2] = w4.z; Wd[r + 3] = w4.w;
  }
  float bias = dtb[d];
  float Areg[D_STATE], hst[D_STATE];
#pragma unroll
  for (int n = 0; n < D_STATE; ++n) {
    Areg[n] = -__expf(A_log[d * D_STATE + n]);
    hst[n] = 0.f;
  }
  bool fast = a_is_arange(Areg);
  float ds = 0.f;
  size_t row0 = (size_t)b * SEQ;
  for (int t = t0; t < t1; ++t) {
    size_t m = row0 + t;
    const float* xq = xdb + m * 64;
    unsigned short dh = f2h(dt_eval(xq, Wd, bias));
    dt[m * D_INNER + d] = dh;
    float dtv = h2f(dh);  // use the ROUNDED value everywhere (consistent with p2)
    float uv = b2f(ub[m * D_INNER + d]);
    float Bv[D_STATE];
#pragma unroll
    for (int qd = 0; qd < 4; ++qd) {
      float4 v4 = *(const float4*)&xq[32 + qd * 4];
      Bv[qd * 4 + 0] = v4.x; Bv[qd * 4 + 1] = v4.y;
      Bv[qd * 4 + 2] = v4.z; Bv[qd * 4 + 3] = v4.w;
    }
    float du = dtv * uv;
    ds += dtv;
    float e[D_STATE];
    exp_vec(dtv, Areg, fast, e);
#pragma unroll
    for (int j = 0; j < D_STATE; ++j)
      hst[j] = fmaf(e[j], hst[j], du * Bv[j]);
  }
  size_t base = ((size_t)(b * NCH + c) * D_INNER + d) * D_STATE;
  ushort8 o0, o1;
#pragma unroll
  for (int j = 0; j < 8; ++j) { o0[j] = f2b(hst[j]); o1[j] = f2b(hst[8 + j]); }
  *(ushort8*)&L[base] = o0;
  *(ushort8*)&L[base + 8] = o1;
  dtsum[(size_t)(b * NCH + c) * D_INNER + d] = ds;
}

// ---------------- chunked scan: fixup (sequential chunk prefix; L -> entry states) --------
__global__ __launch_bounds__(256) void k_scan_fix(const float* __restrict__ A_log,
                                                  const float* __restrict__ dtsum,
                                                  unsigned short* __restrict__ L) {
  int tid = threadIdx.x;
  int b = blockIdx.x;
  int d = blockIdx.y * 256 + tid;
  float Areg[D_STATE], h[D_STATE];
#pragma unroll
  for (int n = 0; n < D_STATE; ++n) {
    Areg[n] = -__expf(A_log[d * D_STATE + n]);
    h[n] = 0.f;
  }
  bool fast = a_is_arange(Areg);
  for (int c = 0; c < NCH; ++c) {
    size_t base = ((size_t)(b * NCH + c) * D_INNER + d) * D_STATE;
    ushort8 l0 = *(const ushort8*)&L[base];
    ushort8 l1 = *(const ushort8*)&L[base + 8];
    float ds = dtsum[(size_t)(b * NCH + c) * D_INNER + d];
    ushort8 o0, o1;
#pragma unroll
    for (int j = 0; j < 8; ++j) { o0[j] = f2b(h[j]); o1[j] = f2b(h[8 + j]); }
    *(ushort8*)&L[base] = o0;
    *(ushort8*)&L[base + 8] = o1;
    float e[D_STATE];
    exp_vec(ds, Areg, fast, e);
#pragma unroll
    for (int j = 0; j < 8; ++j)
      h[j] = fmaf(e[j], h[j], b2f(l0[j]));
#pragma unroll
    for (int j = 0; j < 8; ++j)
      h[8 + j] = fmaf(e[8 + j], h[8 + j], b2f(l1[j]));
  }
}

// ---------------- chunked scan: pass 2 (entry state from fixed-up L) ----------------
__global__ __launch_bounds__(256) void k_scan_p2(const unsigned short* __restrict__ xz,
                                                 const unsigned short* __restrict__ ub,
                                                 const float* __restrict__ xdb,
                                                 const unsigned short* __restrict__ dt,
                                                 const float* __restrict__ A_log,
                                                 const float* __restrict__ Dv,
                                                 const unsigned short* __restrict__ L,
                                                 unsigned short* __restrict__ yb) {
  int tid = threadIdx.x;
  int b = blockIdx.x >> 3, c = blockIdx.x & 7;
  int d = blockIdx.y * 256 + tid;
  int t0 = c * CL, t1 = t0 + CL < SEQ ? t0 + CL : SEQ;
  float Areg[D_STATE], hst[D_STATE];
  size_t base = ((size_t)(b * NCH + c) * D_INNER + d) * D_STATE;
  ushort8 l0 = *(const ushort8*)&L[base];
  ushort8 l1 = *(const ushort8*)&L[base + 8];
#pragma unroll
  for (int n = 0; n < D_STATE; ++n) Areg[n] = -__expf(A_log[d * D_STATE + n]);
  bool fast = a_is_arange(Areg);
#pragma unroll
  for (int j = 0; j < 8; ++j) { hst[j] = b2f(l0[j]); hst[8 + j] = b2f(l1[j]); }
  float Dd = Dv[d];
  size_t row0 = (size_t)b * SEQ;
  for (int t = t0; t < t1; ++t) {
    size_t m = row0 + t;
    const float* xq = xdb + m * 64;
    float dtv = h2f(dt[m * D_INNER + d]);
    float uv = b2f(ub[m * D_INNER + d]);
    float zv = b2f(xz[m * 2048 + 1024 + d]);
    float Bv[D_STATE], Cvv[D_STATE];
#pragma unroll
    for (int qd = 0; qd < 4; ++qd) {
      float4 v4 = *(const float4*)&xq[32 + qd * 4];
      Bv[qd * 4 + 0] = v4.x; Bv[qd * 4 + 1] = v4.y;
      Bv[qd * 4 + 2] = v4.z; Bv[qd * 4 + 3] = v4.w;
      float4 c4 = *(const float4*)&xq[48 + qd * 4];
      Cvv[qd * 4 + 0] = c4.x; Cvv[qd * 4 + 1] = c4.y;
      Cvv[qd * 4 + 2] = c4.z; Cvv[qd * 4 + 3] = c4.w;
    }
    float du = dtv * uv;
    float e[D_STATE];
    exp_vec(dtv, Areg, fast, e);
    float y0 = 0.f, y1 = 0.f, y2 = 0.f, y3 = 0.f;
#pragma unroll
    for (int j = 0; j < D_STATE; ++j) {
      hst[j] = fmaf(e[j], hst[j], du * Bv[j]);
      float& yq = (j < 4) ? y0 : (j < 8) ? y1 : (j < 12) ? y2 : y3;
      yq = fmaf(hst[j], Cvv[j], yq);
    }
    float y = (y0 + y1) + (y2 + y3);
    y = fmaf(Dd, uv, y);
    y = y * (zv * sigmoidf_(zv));
    yb[m * D_INNER + d] = f2b(y);
  }
}

extern "C" void kernel_launch(void* const* d_in, const int* in_sizes, int n_in,
                              void* d_out, int out_size, void* d_ws, size_t ws_size,
                              hipStream_t stream) {
  const float* x        = (const float*)d_in[0];
  const float* embed_W  = (const float*)d_in[2];
  const float* embed_b  = (const float*)d_in[3];
  const float* norm_w   = (const float*)d_in[4];
  const float* norm_b   = (const float*)d_in[5];
  const float* in_W     = (const float*)d_in[6];
  const float* conv_w   = (const float*)d_in[7];
  const float* conv_b   = (const float*)d_in[8];
  const float* xproj_W  = (const float*)d_in[9];
  const float* dtproj_W = (const float*)d_in[10];
  const float* dtproj_b = (const float*)d_in[11];
  const float* A_log    = (const float*)d_in[12];
  const float* Dskip    = (const float*)d_in[13];
  const float* out_W    = (const float*)d_in[14];
  const float* normf_w  = (const float*)d_in[15];
  const float* normf_b  = (const float*)d_in[16];
  const float* head_W   = (const float*)d_in[17];
  float* out = (float*)d_out;

  size_t f32_elems = (size_t)M_ROWS * 512 /* res */ + (size_t)M_PAD * 64 /* xdb */ +
                     (size_t)NB_LAYERS * D_CONV * D_INNER /* cwT */ +
                     (size_t)BATCH * NCH * D_INNER /* dtsum */;
  size_t bf16_elems = (size_t)M_ROWS * 2048 /* xz */ + (size_t)M_PAD * 2048 /* ub+yb */ +
                      (size_t)M_ROWS * 1024 /* dt fp16 */ +
                      (size_t)BATCH * NCH * D_INNER * D_STATE /* L */ +
                      (size_t)NB_LAYERS * (2048 * 512 + 512 * 1024 + 128 * 1024) +
                      256 * 512;
  size_t need = f32_elems * 4 + bf16_elems * 2;
  if (ws_size < need) return;

  float* ws = (float*)d_ws;
  float* buf_res  = ws;                                   // M*512 (residual stream)
  float* buf_xdb  = buf_res  + (size_t)M_ROWS * 512;      // M_PAD*64 fp32
  float* buf_cwT  = buf_xdb  + (size_t)M_PAD * 64;        // 3*4*1024 fp32
  float* buf_dts  = buf_cwT  + (size_t)NB_LAYERS * D_CONV * D_INNER;  // B*NCH*1024 fp32
  unsigned short* buf_xz   = (unsigned short*)(buf_dts + (size_t)BATCH * NCH * D_INNER);
  unsigned short* buf_ub   = buf_xz + (size_t)M_ROWS * 2048;  // M_PAD*1024
  unsigned short* buf_yb   = buf_ub + (size_t)M_PAD * 1024;   // M_PAD*1024 (alias hnb)
  unsigned short* buf_hnb  = buf_yb;                          // M_PAD*512
  unsigned short* buf_dt   = buf_yb + (size_t)M_PAD * 1024;   // M*1024 fp16
  unsigned short* buf_L    = buf_dt + (size_t)M_ROWS * 1024;  // B*NCH*1024*16 bf16
  unsigned short* buf_wib  = buf_L + (size_t)BATCH * NCH * D_INNER * D_STATE;
  unsigned short* buf_wob  = buf_wib + (size_t)NB_LAYERS * 2048 * 512;
  unsigned short* buf_wxb  = buf_wob + (size_t)NB_LAYERS * 512 * 1024;
  unsigned short* buf_whb  = buf_wxb + (size_t)NB_LAYERS * 128 * 1024;

  dim3 blk(256);

  // ---- all-layer weight prep (5 dispatches, once per launch) ----
  k_f2b<<<(NB_LAYERS * 2048 * 512 + 255) / 256, blk, 0, stream>>>(
      in_W, buf_wib, NB_LAYERS * 2048 * 512, NB_LAYERS * 2048 * 512);
  k_f2b<<<(NB_LAYERS * 512 * 1024 + 255) / 256, blk, 0, stream>>>(
      out_W, buf_wob, NB_LAYERS * 512 * 1024, NB_LAYERS * 512 * 1024);
  k_padR<<<(NB_LAYERS * 128 * 1024 + 255) / 256, blk, 0, stream>>>(
      xproj_W, buf_wxb, NB_LAYERS, 64, 128, 1024);
  k_f2b<<<(256 * 512 + 255) / 256, blk, 0, stream>>>(head_W, buf_whb, CITY * 512, 256 * 512);
  k_convT<<<(NB_LAYERS * D_CONV * D_INNER + 255) / 256, blk, 0, stream>>>(conv_w, buf_cwT);

  // embed -> residual stream
  k_embed<<<(M_ROWS * D_MODEL + 255) / 256, blk, 0, stream>>>(x, embed_W, embed_b, buf_res);

  for (int i = 0; i < NB_LAYERS; ++i) {
    // layernorm(res) -> hn (bf16); res untouched
    k_norm<<<(M_ROWS + 3) / 4, blk, 0, stream>>>(
        buf_res, buf_hnb, norm_w + i * D_MODEL, norm_b + i * D_MODEL, 0);

    // in_proj (MFMA, bf16 out): xz = hn @ in_W^T   (M, 2048)
    k_gemm_mfma<1, 0><<<dim3(2048 / 128, M_PAD / 128), blk, 0, stream>>>(
        buf_hnb, buf_wib + (size_t)i * 2048 * 512, buf_xz, 2048, M_ROWS, 2048, 512);

    // conv + silu -> u (bf16); coalesced transposed weights
    k_conv_silu<<<(M_ROWS * 128 + 255) / 256, blk, 0, stream>>>(
        buf_xz, buf_cwT + (size_t)i * D_CONV * D_INNER, conv_b + (size_t)i * D_INNER, buf_ub);

    // x_proj (MFMA, fp32 out): xdb = u @ xproj_W^T   (M, 64), N padded to 128
    k_gemm_mfma<0, 0><<<dim3(1, M_PAD / 128), blk, 0, stream>>>(
        buf_ub, buf_wxb + (size_t)i * 128 * 1024, buf_xdb, 64, M_ROWS, 64, 1024);

    // chunked scan: p1 -> fixup -> p2
    const float* Ai  = A_log + (size_t)i * D_INNER * D_STATE;
    const float* Wdt = dtproj_W + (size_t)i * D_INNER * DT_RANK;
    const float* bdt = dtproj_b + (size_t)i * D_INNER;
    k_scan_p1<<<dim3(BATCH * NCH, D_INNER / 256), blk, 0, stream>>>(
        buf_ub, buf_xdb, Wdt, bdt, Ai, buf_dt, buf_L, buf_dts);
    k_scan_fix<<<dim3(BATCH, D_INNER / 256), blk, 0, stream>>>(Ai, buf_dts, buf_L);
    k_scan_p2<<<dim3(BATCH * NCH, D_INNER / 256), blk, 0, stream>>>(
        buf_xz, buf_ub, buf_xdb, buf_dt, Ai, Dskip + (size_t)i * D_INNER, buf_L, buf_yb);

    // out_proj (MFMA, residual-fused): res += y @ out_W^T   (M, 512)
    k_gemm_mfma<0, 1><<<dim3(512 / 128, M_PAD / 128), blk, 0, stream>>>(
        buf_yb, buf_wob + (size_t)i * 512 * 1024, buf_res, 512, M_ROWS, 512, 1024);
  }

  // final rmsnorm(res) -> xf (bf16, over hnb region; y dead)
  k_norm<<<(M_ROWS + 3) / 4, blk, 0, stream>>>(buf_res, buf_hnb, normf_w, normf_b, 1);

  // head (MFMA, fp32 out): logits = xf @ head_W^T   (M, 200), N padded to 256
  k_gemm_mfma<0, 0><<<dim3(256 / 128, M_PAD / 128), blk, 0, stream>>>(
      buf_hnb, buf_whb, out, CITY, M_ROWS, CITY, 512);
}

// Round 22
// 727.809 us; speedup vs baseline: 1.0752x; 1.0191x over previous
//
#include <hip/hip_runtime.h>
#include <hip/hip_fp16.h>
#include <math.h>

#define D_MODEL 512
#define D_INNER 1024
#define DT_RANK 32
#define D_STATE 16
#define D_CONV 4
#define NB_LAYERS 3
#define BATCH 64
#define SEQ 201
#define CITY 200
#define M_ROWS (BATCH * SEQ)   // 12864 = 64*201
#define M_PAD 12928            // 128*101, for 128-row MFMA tiles
#define EPS 1e-5f
#define NCH 8                  // scan chunks
#define CL 26                  // chunk length (8*26=208 >= 201)

typedef __attribute__((ext_vector_type(8))) short short8;
typedef __attribute__((ext_vector_type(8))) unsigned short ushort8;
typedef __attribute__((ext_vector_type(4))) float f32x4;

__device__ __forceinline__ float sigmoidf_(float x) { return 1.f / (1.f + __expf(-x)); }

__device__ __forceinline__ unsigned short f2b(float f) {  // RNE fp32->bf16
  union { float f; unsigned int u; } v; v.f = f;
  unsigned int r = (v.u + 0x7fff + ((v.u >> 16) & 1)) >> 16;
  return (unsigned short)r;
}
__device__ __forceinline__ float b2f(unsigned short h) {
  union { unsigned int u; float f; } v; v.u = ((unsigned int)h) << 16; return v.f;
}
__device__ __forceinline__ unsigned short f2h(float f) {
  __half h = __float2half(f); return *(unsigned short*)&h;
}
__device__ __forceinline__ float h2f(unsigned short u) {
  __half h = *(__half*)&u; return __half2float(h);
}

__device__ __forceinline__ void gload_lds16(const void* g, void* l) {
  __builtin_amdgcn_global_load_lds(
      (const __attribute__((address_space(1))) void*)g,
      (__attribute__((address_space(3))) void*)l, 16, 0, 0);
}

// ---- decay vector: e[n] = exp(dtv*Areg[n]). Fast path (Areg[n] == -(n+1), the model's
// A_init=arange structure, detected at runtime): one exp + 15 muls instead of 16 exps. ----
__device__ __forceinline__ void exp_vec(float dtv, const float* __restrict__ Areg,
                                        bool fast, float* __restrict__ e) {
  if (fast) {
    float e1 = __expf(-dtv);
    e[0] = e1;
    e[1] = e1 * e1;
    e[2] = e[1] * e1;
    e[3] = e[1] * e[1];
    e[4] = e[3] * e1;
    e[5] = e[3] * e[1];
    e[6] = e[3] * e[2];
    e[7] = e[3] * e[3];
    e[8] = e[7] * e1;
    e[9] = e[7] * e[1];
    e[10] = e[7] * e[2];
    e[11] = e[7] * e[3];
    e[12] = e[7] * e[4];
    e[13] = e[7] * e[5];
    e[14] = e[7] * e[6];
    e[15] = e[7] * e[7];
  } else {
#pragma unroll
    for (int n = 0; n < D_STATE; ++n) e[n] = __expf(dtv * Areg[n]);
  }
}
__device__ __forceinline__ bool a_is_arange(const float* __restrict__ Areg) {
  bool f = true;
#pragma unroll
  for (int n = 0; n < D_STATE; ++n)
    f = f && (fabsf(Areg[n] + (float)(n + 1)) < 1e-4f * (float)(n + 1));
  return f;
}

// ---------------- fp32 -> bf16 bulk convert (zero-pad tail to n_total) ----------------
__global__ __launch_bounds__(256) void k_f2b(const float* __restrict__ in,
                                             unsigned short* __restrict__ out,
                                             int n, int n_total) {
  int i = blockIdx.x * 256 + threadIdx.x;
  if (i < n) out[i] = f2b(in[i]);
  else if (i < n_total) out[i] = 0;
}

// ---------------- fp32 [nl][inrows][cols] -> bf16 [nl][outrows][cols], zero row-pad ---------
__global__ __launch_bounds__(256) void k_padR(const float* __restrict__ W,
                                              unsigned short* __restrict__ out,
                                              int nl, int inrows, int outrows, int cols) {
  int i = blockIdx.x * 256 + threadIdx.x;
  if (i >= nl * outrows * cols) return;
  int c = i % cols;
  int r = (i / cols) % outrows;
  int L = i / (cols * outrows);
  out[i] = (r < inrows) ? f2b(W[((size_t)L * inrows + r) * cols + c]) : 0;
}

// ---------------- conv weight transpose: cw[L][d][k] -> cwT[L][k][d] (fp32) ----------------
__global__ __launch_bounds__(256) void k_convT(const float* __restrict__ cw,
                                               float* __restrict__ cwT) {
  int i = blockIdx.x * 256 + threadIdx.x;
  if (i >= NB_LAYERS * D_CONV * D_INNER) return;
  int d = i & (D_INNER - 1);
  int k = (i >> 10) & 3;
  int L = i >> 12;
  cwT[i] = cw[((size_t)L * D_INNER + d) * D_CONV + k];
}

// ---------------- embed ----------------
__global__ __launch_bounds__(256) void k_embed(const float* __restrict__ x,
                                               const float* __restrict__ W,
                                               const float* __restrict__ b,
                                               float* __restrict__ h) {
  int idx = blockIdx.x * 256 + threadIdx.x;
  if (idx >= M_ROWS * D_MODEL) return;
  int d = idx & (D_MODEL - 1);
  int m = idx >> 9;
  float x0 = x[m * 2 + 0], x1 = x[m * 2 + 1];
  h[idx] = fmaf(x0, W[d * 2 + 0], fmaf(x1, W[d * 2 + 1], b[d]));
}

// ---------------- fused residual add + LayerNorm / RMSNorm ----------------
__global__ __launch_bounds__(256) void k_resid_norm(const float* __restrict__ h,
                                                    float* __restrict__ resid,
                                                    float* __restrict__ out,
                                                    unsigned short* __restrict__ out_b,
                                                    const float* __restrict__ w,
                                                    const float* __restrict__ b,
                                                    int addRes, int mode) {
  int row = blockIdx.x * 4 + (threadIdx.x >> 6);
  int lane = threadIdx.x & 63;
  if (row >= M_ROWS) return;
  const float* hp = h + (size_t)row * D_MODEL;
  float* rp = resid + (size_t)row * D_MODEL;
  float v[8];
#pragma unroll
  for (int j = 0; j < 8; ++j) {
    float t = hp[j * 64 + lane];
    if (addRes) t += rp[j * 64 + lane];
    v[j] = t;
    rp[j * 64 + lane] = t;
  }
  float mu = 0.f, rstd;
  if (mode == 0) {
    float s = 0.f;
#pragma unroll
    for (int j = 0; j < 8; ++j) s += v[j];
#pragma unroll
    for (int o = 1; o < 64; o <<= 1) s += __shfl_xor(s, o);
    mu = s * (1.f / D_MODEL);
    float vs = 0.f;
#pragma unroll
    for (int j = 0; j < 8; ++j) { float d0 = v[j] - mu; vs += d0 * d0; }
#pragma unroll
    for (int o = 1; o < 64; o <<= 1) vs += __shfl_xor(vs, o);
    rstd = rsqrtf(vs * (1.f / D_MODEL) + EPS);
  } else {
    float s = 0.f;
#pragma unroll
    for (int j = 0; j < 8; ++j) s += v[j] * v[j];
#pragma unroll
    for (int o = 1; o < 64; o <<= 1) s += __shfl_xor(s, o);
    rstd = rsqrtf(s * (1.f / D_MODEL) + EPS);
  }
#pragma unroll
  for (int j = 0; j < 8; ++j) {
    int c = j * 64 + lane;
    float o = (v[j] - mu) * rstd * w[c] + b[c];
    if (out) out[(size_t)row * D_MODEL + c] = o;
    if (out_b) out_b[(size_t)row * D_MODEL + c] = f2b(o);
  }
}

// ---------------- bf16 MFMA GEMM (m97 structure + T1 XCD swizzle + T2 LDS swizzle) ----------
template <int BOUT>
__global__ __launch_bounds__(256) void k_gemm_mfma(const unsigned short* __restrict__ A,
                                                   const unsigned short* __restrict__ B,
                                                   void* __restrict__ Cv, int ldc,
                                                   int M, int Nout, int K) {
  __shared__ unsigned short lA[128 * 64];
  __shared__ unsigned short lB[128 * 64];
  int tid = threadIdx.x;
  int wave = tid >> 6, lane = tid & 63;
  // T1: bijective XCD-aware block swizzle (m204)
  int nx = gridDim.x;
  int nwg = nx * gridDim.y;
  int bid = blockIdx.y * nx + blockIdx.x;
  int q = nwg >> 3, rr = nwg & 7;
  int xcd = bid & 7, idx = bid >> 3;
  int swz = (xcd < rr ? xcd * (q + 1) : rr * (q + 1) + (xcd - rr) * q) + idx;
  int bm = (swz / nx) * 128, bn = (swz % nx) * 128;
  int wm = (wave >> 1) * 64, wn = (wave & 1) * 64;
  f32x4 acc[4][4] = {};

  for (int k0 = 0; k0 < K; k0 += 64) {
#pragma unroll
    for (int i = 0; i < 4; ++i) {
      int e = (i * 256 + tid) * 8;   // flat bf16 elem in [128][64] tile (linear LDS dest)
      int r = e >> 6, c = e & 63;
      int csrc = c ^ ((r & 7) << 3);  // inverse-swizzled global source (involution)
      gload_lds16(A + (size_t)(bm + r) * K + k0 + csrc, &lA[e]);
      gload_lds16(B + (size_t)(bn + r) * K + k0 + csrc, &lB[e]);
    }
    __syncthreads();
#pragma unroll
    for (int ks = 0; ks < 2; ++ks) {
      int koff = ks * 32 + (lane >> 4) * 8;
      short8 a[4], b[4];
#pragma unroll
      for (int i = 0; i < 4; ++i) {
        int row = wm + i * 16 + (lane & 15);
        a[i] = *(const short8*)&lA[row * 64 + (koff ^ ((row & 7) << 3))];
      }
#pragma unroll
      for (int j = 0; j < 4; ++j) {
        int row = wn + j * 16 + (lane & 15);
        b[j] = *(const short8*)&lB[row * 64 + (koff ^ ((row & 7) << 3))];
      }
#pragma unroll
      for (int i = 0; i < 4; ++i)
#pragma unroll
        for (int j = 0; j < 4; ++j)
          acc[i][j] = __builtin_amdgcn_mfma_f32_16x16x32_bf16(a[i], b[j], acc[i][j], 0, 0, 0);
    }
    __syncthreads();
  }
  // C/D layout: col = lane&15, row = (lane>>4)*4 + reg   [m89-verified]
#pragma unroll
  for (int i = 0; i < 4; ++i) {
    int row0 = bm + wm + i * 16 + (lane >> 4) * 4;
#pragma unroll
    for (int j = 0; j < 4; ++j) {
      int col = bn + wn + j * 16 + (lane & 15);
#pragma unroll
      for (int r = 0; r < 4; ++r) {
        int m = row0 + r;
        if (m < M && col < Nout) {
          float v = acc[i][j][r];
          if (BOUT == 1) ((unsigned short*)Cv)[(size_t)m * ldc + col] = f2b(v);
          else ((float*)Cv)[(size_t)m * ldc + col] = v;
        }
      }
    }
  }
}

// ---------------- depthwise causal conv (width 4) + bias + SiLU; 8 d per thread ------------
__global__ __launch_bounds__(256) void k_conv_silu(const unsigned short* __restrict__ xz,
                                                   const float* __restrict__ cwT,
                                                   const float* __restrict__ cb,
                                                   unsigned short* __restrict__ ub) {
  int i = blockIdx.x * 256 + threadIdx.x;
  if (i >= M_ROWS * 128) return;
  int dg = (i & 127) << 3;
  int m = i >> 7;
  int l = m % SEQ;
  float y[8];
  float4 cb0 = *(const float4*)&cb[dg];
  float4 cb1 = *(const float4*)&cb[dg + 4];
  y[0] = cb0.x; y[1] = cb0.y; y[2] = cb0.z; y[3] = cb0.w;
  y[4] = cb1.x; y[5] = cb1.y; y[6] = cb1.z; y[7] = cb1.w;
#pragma unroll
  for (int k = 0; k < D_CONV; ++k) {
    int ls = l - (D_CONV - 1) + k;
    if (ls >= 0) {
      ushort8 xv = *(const ushort8*)&xz[(size_t)(m - (D_CONV - 1) + k) * 2048 + dg];
      float4 w0 = *(const float4*)&cwT[k * D_INNER + dg];
      float4 w1 = *(const float4*)&cwT[k * D_INNER + dg + 4];
      y[0] = fmaf(w0.x, b2f(xv[0]), y[0]);
      y[1] = fmaf(w0.y, b2f(xv[1]), y[1]);
      y[2] = fmaf(w0.z, b2f(xv[2]), y[2]);
      y[3] = fmaf(w0.w, b2f(xv[3]), y[3]);
      y[4] = fmaf(w1.x, b2f(xv[4]), y[4]);
      y[5] = fmaf(w1.y, b2f(xv[5]), y[5]);
      y[6] = fmaf(w1.z, b2f(xv[6]), y[6]);
      y[7] = fmaf(w1.w, b2f(xv[7]), y[7]);
    }
  }
  ushort8 o;
#pragma unroll
  for (int j = 0; j < 8; ++j) { float v = y[j]; v = v * sigmoidf_(v); o[j] = f2b(v); }
  *(ushort8*)&ub[(size_t)m * D_INNER + dg] = o;
}

// ---- fused dt: dot(dt_r, Wd)+bias -> softplus; dt_r = fp32 xdb cols 0..31 (wave-uniform) ---
__device__ __forceinline__ float dt_eval(const float* __restrict__ xq,
                                         const float* __restrict__ Wd, float bias) {
  float a0 = 0.f, a1 = 0.f, a2 = 0.f, a3 = 0.f;
#pragma unroll
  for (int r = 0; r < 2; ++r) {
    float4 q0 = *(const float4*)&xq[r * 16 + 0];
    float4 q1 = *(const float4*)&xq[r * 16 + 4];
    float4 q2 = *(const float4*)&xq[r * 16 + 8];
    float4 q3 = *(const float4*)&xq[r * 16 + 12];
    int o = r * 16;
    a0 = fmaf(q0.x, Wd[o + 0], a0); a0 = fmaf(q0.y, Wd[o + 1], a0);
    a0 = fmaf(q0.z, Wd[o + 2], a0); a0 = fmaf(q0.w, Wd[o + 3], a0);
    a1 = fmaf(q1.x, Wd[o + 4], a1); a1 = fmaf(q1.y, Wd[o + 5], a1);
    a1 = fmaf(q1.z, Wd[o + 6], a1); a1 = fmaf(q1.w, Wd[o + 7], a1);
    a2 = fmaf(q2.x, Wd[o + 8], a2); a2 = fmaf(q2.y, Wd[o + 9], a2);
    a2 = fmaf(q2.z, Wd[o + 10], a2); a2 = fmaf(q2.w, Wd[o + 11], a2);
    a3 = fmaf(q3.x, Wd[o + 12], a3); a3 = fmaf(q3.y, Wd[o + 13], a3);
    a3 = fmaf(q3.z, Wd[o + 14], a3); a3 = fmaf(q3.w, Wd[o + 15], a3);
  }
  float dot = ((a0 + a1) + (a2 + a3)) + bias;
  return (dot > 20.f) ? dot : __logf(1.f + __expf(dot));
}

// ---------------- chunked scan: pass 1 (local scans, h0=0; computes+stores dt fp16) --------
__global__ __launch_bounds__(256) void k_scan_p1(const unsigned short* __restrict__ ub,
                                                 const float* __restrict__ xdb,
                                                 const float* __restrict__ dtW,
                                                 const float* __restrict__ dtb,
                                                 const float* __restrict__ A_log,
                                                 unsigned short* __restrict__ dt,
                                                 unsigned short* __restrict__ L,
                                                 float* __restrict__ dtsum) {
  int tid = threadIdx.x;
  int b = blockIdx.x >> 3, c = blockIdx.x & 7;
  int d = blockIdx.y * 256 + tid;
  int t0 = c * CL, t1 = t0 + CL < SEQ ? t0 + CL : SEQ;
  float Wd[DT_RANK];
#pragma unroll
  for (int r = 0; r < DT_RANK; r += 4) {
    float4 w4 = *(const float4*)&dtW[(size_t)d * DT_RANK + r];
    Wd[r] = w4.x; Wd[r + 1] = w4.y; Wd[r + 2] = w4.z; Wd[r + 3] = w4.w;
  }
  float bias = dtb[d];
  float Areg[D_STATE], hst[D_STATE];
#pragma unroll
  for (int n = 0; n < D_STATE; ++n) {
    Areg[n] = -__expf(A_log[d * D_STATE + n]);
    hst[n] = 0.f;
  }
  bool fast = a_is_arange(Areg);
  float ds = 0.f;
  size_t row0 = (size_t)b * SEQ;
  for (int t = t0; t < t1; ++t) {
    size_t m = row0 + t;
    const float* xq = xdb + m * 64;
    unsigned short dh = f2h(dt_eval(xq, Wd, bias));
    dt[m * D_INNER + d] = dh;
    float dtv = h2f(dh);  // use the ROUNDED value everywhere (consistent with p2)
    float uv = b2f(ub[m * D_INNER + d]);
    float Bv[D_STATE];
#pragma unroll
    for (int qd = 0; qd < 4; ++qd) {
      float4 v4 = *(const float4*)&xq[32 + qd * 4];
      Bv[qd * 4 + 0] = v4.x; Bv[qd * 4 + 1] = v4.y;
      Bv[qd * 4 + 2] = v4.z; Bv[qd * 4 + 3] = v4.w;
    }
    float du = dtv * uv;
    ds += dtv;
    float e[D_STATE];
    exp_vec(dtv, Areg, fast, e);
#pragma unroll
    for (int j = 0; j < D_STATE; ++j)
      hst[j] = fmaf(e[j], hst[j], du * Bv[j]);
  }
  size_t base = ((size_t)(b * NCH + c) * D_INNER + d) * D_STATE;
  ushort8 o0, o1;
#pragma unroll
  for (int j = 0; j < 8; ++j) { o0[j] = f2b(hst[j]); o1[j] = f2b(hst[8 + j]); }
  *(ushort8*)&L[base] = o0;
  *(ushort8*)&L[base + 8] = o1;
  dtsum[(size_t)(b * NCH + c) * D_INNER + d] = ds;
}

// ---------------- chunked scan: fixup (sequential chunk prefix; L -> entry states) --------
__global__ __launch_bounds__(256) void k_scan_fix(const float* __restrict__ A_log,
                                                  const float* __restrict__ dtsum,
                                                  unsigned short* __restrict__ L) {
  int tid = threadIdx.x;
  int b = blockIdx.x;
  int d = blockIdx.y * 256 + tid;
  float Areg[D_STATE], h[D_STATE];
#pragma unroll
  for (int n = 0; n < D_STATE; ++n) {
    Areg[n] = -__expf(A_log[d * D_STATE + n]);
    h[n] = 0.f;
  }
  bool fast = a_is_arange(Areg);
  for (int c = 0; c < NCH; ++c) {
    size_t base = ((size_t)(b * NCH + c) * D_INNER + d) * D_STATE;
    ushort8 l0 = *(const ushort8*)&L[base];
    ushort8 l1 = *(const ushort8*)&L[base + 8];
    float ds = dtsum[(size_t)(b * NCH + c) * D_INNER + d];
    ushort8 o0, o1;
#pragma unroll
    for (int j = 0; j < 8; ++j) { o0[j] = f2b(h[j]); o1[j] = f2b(h[8 + j]); }
    *(ushort8*)&L[base] = o0;
    *(ushort8*)&L[base + 8] = o1;
    float e[D_STATE];
    exp_vec(ds, Areg, fast, e);
#pragma unroll
    for (int j = 0; j < 8; ++j)
      h[j] = fmaf(e[j], h[j], b2f(l0[j]));
#pragma unroll
    for (int j = 0; j < 8; ++j)
      h[8 + j] = fmaf(e[8 + j], h[8 + j], b2f(l1[j]));
  }
}

// ---------------- chunked scan: pass 2 (full scan per chunk; loads dt, no recompute) -------
__global__ __launch_bounds__(256) void k_scan_p2(const unsigned short* __restrict__ xz,
                                                 const unsigned short* __restrict__ ub,
                                                 const float* __restrict__ xdb,
                                                 const unsigned short* __restrict__ dt,
                                                 const float* __restrict__ A_log,
                                                 const float* __restrict__ Dv,
                                                 const unsigned short* __restrict__ L,
                                                 unsigned short* __restrict__ yb) {
  int tid = threadIdx.x;
  int b = blockIdx.x >> 3, c = blockIdx.x & 7;
  int d = blockIdx.y * 256 + tid;
  int t0 = c * CL, t1 = t0 + CL < SEQ ? t0 + CL : SEQ;
  float Areg[D_STATE], hst[D_STATE];
  size_t base = ((size_t)(b * NCH + c) * D_INNER + d) * D_STATE;
  ushort8 l0 = *(const ushort8*)&L[base];
  ushort8 l1 = *(const ushort8*)&L[base + 8];
#pragma unroll
  for (int n = 0; n < D_STATE; ++n) Areg[n] = -__expf(A_log[d * D_STATE + n]);
  bool fast = a_is_arange(Areg);
#pragma unroll
  for (int j = 0; j < 8; ++j) { hst[j] = b2f(l0[j]); hst[8 + j] = b2f(l1[j]); }
  float Dd = Dv[d];
  size_t row0 = (size_t)b * SEQ;
  for (int t = t0; t < t1; ++t) {
    size_t m = row0 + t;
    const float* xq = xdb + m * 64;
    float dtv = h2f(dt[m * D_INNER + d]);
    float uv = b2f(ub[m * D_INNER + d]);
    float zv = b2f(xz[m * 2048 + 1024 + d]);
    float Bv[D_STATE], Cvv[D_STATE];
#pragma unroll
    for (int qd = 0; qd < 4; ++qd) {
      float4 v4 = *(const float4*)&xq[32 + qd * 4];
      Bv[qd * 4 + 0] = v4.x; Bv[qd * 4 + 1] = v4.y;
      Bv[qd * 4 + 2] = v4.z; Bv[qd * 4 + 3] = v4.w;
      float4 c4 = *(const float4*)&xq[48 + qd * 4];
      Cvv[qd * 4 + 0] = c4.x; Cvv[qd * 4 + 1] = c4.y;
      Cvv[qd * 4 + 2] = c4.z; Cvv[qd * 4 + 3] = c4.w;
    }
    float du = dtv * uv;
    float e[D_STATE];
    exp_vec(dtv, Areg, fast, e);
    float y0 = 0.f, y1 = 0.f, y2 = 0.f, y3 = 0.f;
#pragma unroll
    for (int j = 0; j < D_STATE; ++j) {
      hst[j] = fmaf(e[j], hst[j], du * Bv[j]);
      float& yq = (j < 4) ? y0 : (j < 8) ? y1 : (j < 12) ? y2 : y3;
      yq = fmaf(hst[j], Cvv[j], yq);
    }
    float y = (y0 + y1) + (y2 + y3);
    y = fmaf(Dd, uv, y);
    y = y * (zv * sigmoidf_(zv));
    yb[m * D_INNER + d] = f2b(y);
  }
}

extern "C" void kernel_launch(void* const* d_in, const int* in_sizes, int n_in,
                              void* d_out, int out_size, void* d_ws, size_t ws_size,
                              hipStream_t stream) {
  const float* x        = (const float*)d_in[0];
  const float* embed_W  = (const float*)d_in[2];
  const float* embed_b  = (const float*)d_in[3];
  const float* norm_w   = (const float*)d_in[4];
  const float* norm_b   = (const float*)d_in[5];
  const float* in_W     = (const float*)d_in[6];
  const float* conv_w   = (const float*)d_in[7];
  const float* conv_b   = (const float*)d_in[8];
  const float* xproj_W  = (const float*)d_in[9];
  const float* dtproj_W = (const float*)d_in[10];
  const float* dtproj_b = (const float*)d_in[11];
  const float* A_log    = (const float*)d_in[12];
  const float* Dskip    = (const float*)d_in[13];
  const float* out_W    = (const float*)d_in[14];
  const float* normf_w  = (const float*)d_in[15];
  const float* normf_b  = (const float*)d_in[16];
  const float* head_W   = (const float*)d_in[17];
  float* out = (float*)d_out;

  size_t f32_elems = (size_t)M_ROWS * 1024 /* res+h */ + (size_t)M_PAD * 64 /* xdb fp32 */ +
                     (size_t)NB_LAYERS * D_CONV * D_INNER;
  size_t bf16_elems = (size_t)M_ROWS * 2048 + (size_t)M_PAD * 2048 +
                      (size_t)M_ROWS * 1024 /* dt fp16 */ +
                      (size_t)NB_LAYERS * (2048 * 512 + 512 * 1024 + 128 * 1024) +
                      256 * 512;
  size_t need = f32_elems * 4 + bf16_elems * 2;
  if (ws_size < need) return;

  float* ws = (float*)d_ws;
  float* buf_res  = ws;                                   // M*512
  float* buf_h    = buf_res  + (size_t)M_ROWS * 512;      // M*512 (scan scratch L+dtsum)
  float* buf_xdb  = buf_h    + (size_t)M_ROWS * 512;      // M_PAD*64 fp32
  float* buf_cwT  = buf_xdb  + (size_t)M_PAD * 64;        // 3*4*1024 fp32
  unsigned short* buf_xz   = (unsigned short*)(buf_cwT + (size_t)NB_LAYERS * D_CONV * D_INNER);
  unsigned short* buf_ub   = buf_xz + (size_t)M_ROWS * 2048;  // M_PAD*1024
  unsigned short* buf_yb   = buf_ub + (size_t)M_PAD * 1024;   // M_PAD*1024 (alias hnb)
  unsigned short* buf_hnb  = buf_yb;                          // M_PAD*512
  unsigned short* buf_dt   = buf_yb + (size_t)M_PAD * 1024;   // M*1024 fp16
  unsigned short* buf_wib  = buf_dt + (size_t)M_ROWS * 1024;  // 3*2048*512
  unsigned short* buf_wob  = buf_wib + (size_t)NB_LAYERS * 2048 * 512;  // 3*512*1024
  unsigned short* buf_wxb  = buf_wob + (size_t)NB_LAYERS * 512 * 1024;  // 3*128*1024
  unsigned short* buf_whb  = buf_wxb + (size_t)NB_LAYERS * 128 * 1024;  // 256*512

  // scan scratch inside dead buf_h: L bf16 (16.8MB) + dtsum fp32 (2MB) < 26.3MB
  unsigned short* buf_L = (unsigned short*)buf_h;
  float* buf_dts = (float*)(buf_L + (size_t)BATCH * NCH * D_INNER * D_STATE);

  dim3 blk(256);

  // ---- all-layer weight prep (5 dispatches, once per launch) ----
  k_f2b<<<(NB_LAYERS * 2048 * 512 + 255) / 256, blk, 0, stream>>>(
      in_W, buf_wib, NB_LAYERS * 2048 * 512, NB_LAYERS * 2048 * 512);
  k_f2b<<<(NB_LAYERS * 512 * 1024 + 255) / 256, blk, 0, stream>>>(
      out_W, buf_wob, NB_LAYERS * 512 * 1024, NB_LAYERS * 512 * 1024);
  k_padR<<<(NB_LAYERS * 128 * 1024 + 255) / 256, blk, 0, stream>>>(
      xproj_W, buf_wxb, NB_LAYERS, 64, 128, 1024);
  k_f2b<<<(256 * 512 + 255) / 256, blk, 0, stream>>>(head_W, buf_whb, CITY * 512, 256 * 512);
  k_convT<<<(NB_LAYERS * D_CONV * D_INNER + 255) / 256, blk, 0, stream>>>(conv_w, buf_cwT);

  k_embed<<<(M_ROWS * D_MODEL + 255) / 256, blk, 0, stream>>>(x, embed_W, embed_b, buf_h);

  for (int i = 0; i < NB_LAYERS; ++i) {
    // residual update + layernorm -> hn (bf16)
    k_resid_norm<<<(M_ROWS + 3) / 4, blk, 0, stream>>>(
        buf_h, buf_res, nullptr, buf_hnb, norm_w + i * D_MODEL, norm_b + i * D_MODEL,
        i > 0 ? 1 : 0, 0);

    // in_proj (MFMA, bf16 out): xz = hn @ in_W^T   (M, 2048)
    k_gemm_mfma<1><<<dim3(2048 / 128, M_PAD / 128), blk, 0, stream>>>(
        buf_hnb, buf_wib + (size_t)i * 2048 * 512, buf_xz, 2048, M_ROWS, 2048, 512);

    // conv + silu -> u (bf16); coalesced transposed weights
    k_conv_silu<<<(M_ROWS * 128 + 255) / 256, blk, 0, stream>>>(
        buf_xz, buf_cwT + (size_t)i * D_CONV * D_INNER, conv_b + (size_t)i * D_INNER, buf_ub);

    // x_proj (MFMA, fp32 out): xdb = u @ xproj_W^T   (M, 64), N padded to 128
    k_gemm_mfma<0><<<dim3(1, M_PAD / 128), blk, 0, stream>>>(
        buf_ub, buf_wxb + (size_t)i * 128 * 1024, buf_xdb, 64, M_ROWS, 64, 1024);

    // chunked scan (fused dt in p1, stored fp16; p2 reuses): pass1 -> fixup -> pass2
    const float* Ai  = A_log + (size_t)i * D_INNER * D_STATE;
    const float* Wdt = dtproj_W + (size_t)i * D_INNER * DT_RANK;
    const float* bdt = dtproj_b + (size_t)i * D_INNER;
    k_scan_p1<<<dim3(BATCH * NCH, D_INNER / 256), blk, 0, stream>>>(
        buf_ub, buf_xdb, Wdt, bdt, Ai, buf_dt, buf_L, buf_dts);
    k_scan_fix<<<dim3(BATCH, D_INNER / 256), blk, 0, stream>>>(Ai, buf_dts, buf_L);
    k_scan_p2<<<dim3(BATCH * NCH, D_INNER / 256), blk, 0, stream>>>(
        buf_xz, buf_ub, buf_xdb, buf_dt, Ai, Dskip + (size_t)i * D_INNER, buf_L, buf_yb);

    // out_proj (MFMA, fp32 out): h = y @ out_W^T   (M, 512)  — overwrites scan scratch
    k_gemm_mfma<0><<<dim3(512 / 128, M_PAD / 128), blk, 0, stream>>>(
        buf_yb, buf_wob + (size_t)i * 512 * 1024, buf_h, 512, M_ROWS, 512, 1024);
  }

  // final residual + rmsnorm -> xf (bf16, over hnb region; y dead)
  k_resid_norm<<<(M_ROWS + 3) / 4, blk, 0, stream>>>(
      buf_h, buf_res, nullptr, buf_hnb, normf_w, normf_b, 1, 1);

  // head (MFMA, fp32 out): logits = xf @ head_W^T   (M, 200), N padded to 256
  k_gemm_mfma<0><<<dim3(256 / 128, M_PAD / 128), blk, 0, stream>>>(
      buf_hnb, buf_whb, out, CITY, M_ROWS, CITY, 512);
}